// Round 2
// baseline (2248.640 us; speedup 1.0000x reference)
//
#include <hip/hip_runtime.h>
#include <stdint.h>
#include <stddef.h>

// BoltzmannMachine: 32 iters of act = relu(act @ (W*A^T)^T); act[:,:1024]=x;
// hid = act[:,2048:] row-normalized.
// R2: (1) C0 = x-part precomputed once (K 4096->3072 per iter);
//     (2) 2-stage LDS dbuf, single barrier per k-step (hide global->LDS latency);
//     (3) normalization folded into GEMM via split accumulators (accA out-k, accB hid-k)
//         and prev-iter scale s[b]; hid stored unnormalized, final scale in finalize.

#define L 4096
#define INX 1024
#define OUTX 1024
#define BATCH 1024
#define NCOL 3072
#define NITER 32

#define BM 128
#define BN 96
#define BK 64

typedef float floatx4 __attribute__((ext_vector_type(4)));
typedef short bf16x8 __attribute__((ext_vector_type(8)));

__device__ __forceinline__ unsigned short f2bf(float f) {
  unsigned int u = __float_as_uint(f);
  u += 0x7FFF + ((u >> 16) & 1);   // RNE
  return (unsigned short)(u >> 16);
}
__device__ __forceinline__ float bf2f(unsigned short h) {
  return __uint_as_float(((unsigned int)h) << 16);
}

__device__ __forceinline__ void load_lds_16B(const void* g, void* s) {
  __builtin_amdgcn_global_load_lds(
      (const __attribute__((address_space(1))) unsigned int*)g,
      (__attribute__((address_space(3))) unsigned int*)s, 16, 0, 0);
}

// ---- prep: mwn[i][j] = W[1024+i][j] * A[j][1024+i]  (bf16, 3072x4096) ----
__global__ void prep_mwn(const float* __restrict__ W, const float* __restrict__ A,
                         unsigned short* __restrict__ mwn) {
  __shared__ float At[32][33];
  const int tx = threadIdx.x & 31, ty = threadIdx.x >> 5;
  const int j0 = blockIdx.x * 32, i0 = blockIdx.y * 32;
#pragma unroll
  for (int r = 0; r < 4; ++r) {
    int a = ty + 8 * r;
    At[a][tx] = A[(size_t)(j0 + a) * L + INX + i0 + tx];
  }
  __syncthreads();
#pragma unroll
  for (int r = 0; r < 4; ++r) {
    int ii = ty + 8 * r;
    float w = W[(size_t)(INX + i0 + ii) * L + j0 + tx];
    float av = At[tx][ii];
    mwn[(size_t)(i0 + ii) * L + j0 + tx] = f2bf(w * av);
  }
}

// ---- init actA: cols<1024 = bf16(x), else 0 ----
__global__ void init_act(const float* __restrict__ x, unsigned short* __restrict__ actA) {
  int i = blockIdx.x * 256 + threadIdx.x;
  int col = i & (L - 1), row = i >> 12;
  actA[i] = (col < INX) ? f2bf(x[(size_t)row * INX + col]) : (unsigned short)0;
}

// staging: thread t loads 16B; LDS dest lane-contiguous (global_load_lds requirement);
// global chunk XOR-swizzled by row&7 so ds_read_b128 fragment reads are conflict-free.
__device__ __forceinline__ void stage(unsigned short* As, unsigned short* Bs,
                                      const unsigned short* gA, const unsigned short* gB,
                                      int kb, int srow, int schunk) {
#pragma unroll
  for (int q = 0; q < 4; ++q)
    load_lds_16B(gA + (size_t)q * 32 * L + kb, &As[(q * 32 + srow) * BK + schunk * 8]);
#pragma unroll
  for (int q = 0; q < 3; ++q)
    load_lds_16B(gB + (size_t)q * 32 * L + kb, &Bs[(q * 32 + srow) * BK + schunk * 8]);
}

__device__ __forceinline__ void mfma_step(const unsigned short* As, const unsigned short* Bs,
                                          int wm, int wn, int l15, int quad,
                                          floatx4 acc[4][3]) {
#pragma unroll
  for (int kk = 0; kk < 2; ++kk) {
    bf16x8 af[4], bfr[3];
    const int c = kk * 4 + quad;
#pragma unroll
    for (int mt = 0; mt < 4; ++mt) {
      int r = wm + mt * 16 + l15;
      af[mt] = *(const bf16x8*)&As[r * BK + ((c ^ (r & 7)) * 8)];
    }
#pragma unroll
    for (int nt = 0; nt < 3; ++nt) {
      int r = wn + nt * 16 + l15;
      bfr[nt] = *(const bf16x8*)&Bs[r * BK + ((c ^ (r & 7)) * 8)];
    }
#pragma unroll
    for (int mt = 0; mt < 4; ++mt)
#pragma unroll
      for (int nt = 0; nt < 3; ++nt)
        acc[mt][nt] = __builtin_amdgcn_mfma_f32_16x16x32_bf16(af[mt], bfr[nt],
                                                              acc[mt][nt], 0, 0, 0);
  }
}

// MODE 0: C0 pass, K=[0,1024), c0 = x-part (fp32 store, no relu).
// MODE 1: iter pass, K=[1024,4096), acc split at k=2048 (accA out / accB hid),
//         result = C0 + accA + s_prev[m]*accB, relu, bf16 store, hid sumsq atomics.
template<int MODE>
__global__ __launch_bounds__(256, 1) void gemm_k(
    const unsigned short* __restrict__ act,
    const unsigned short* __restrict__ mwn,
    unsigned short* __restrict__ actn,
    float* __restrict__ c0,
    const float* __restrict__ nsq_prev,
    float* __restrict__ nsq_next) {
  __shared__ alignas(16) unsigned short As[2][BM * BK];
  __shared__ alignas(16) unsigned short Bs[2][BN * BK];
  const int t = threadIdx.x;
  const int lane = t & 63;
  const int wave = t >> 6;
  const int wm = (wave >> 1) * 64;
  const int wn = (wave & 1) * 48;
  const int l15 = lane & 15;
  const int quad = lane >> 4;
  const int m0 = blockIdx.y * BM;
  const int n0 = blockIdx.x * BN;

  const int srow = t >> 3;
  const int schunk = t & 7;
  const int gchunk = schunk ^ (srow & 7);
  const unsigned short* gA = act + (size_t)(m0 + srow) * L + gchunk * 8;
  const unsigned short* gB = mwn + (size_t)(n0 + srow) * L + gchunk * 8;

  const int KB0 = MODE ? INX : 0;
  const int NS = MODE ? 48 : 16;

  floatx4 accA[4][3], accB[4][3];
#pragma unroll
  for (int i = 0; i < 4; ++i)
#pragma unroll
    for (int j = 0; j < 3; ++j) {
      accA[i][j] = (floatx4){0.f, 0.f, 0.f, 0.f};
      if (MODE) accB[i][j] = (floatx4){0.f, 0.f, 0.f, 0.f};
    }

  stage(As[0], Bs[0], gA, gB, KB0, srow, schunk);
  int s = 0;
  // first sub-loop: MODE0 all 16 steps; MODE1 k=[1024,2048) -> accA
  for (; s < 16; ++s) {
    __syncthreads();  // drains vmcnt -> buf[s&1] ready; prev compute done
    if (s + 1 < NS)
      stage(As[(s + 1) & 1], Bs[(s + 1) & 1], gA, gB, KB0 + (s + 1) * BK, srow, schunk);
    mfma_step(As[s & 1], Bs[s & 1], wm, wn, l15, quad, accA);
  }
  if (MODE) {
    // second sub-loop: k=[2048,4096) -> accB (hid contribution, scaled in epilogue)
    for (; s < NS; ++s) {
      __syncthreads();
      if (s + 1 < NS)
        stage(As[(s + 1) & 1], Bs[(s + 1) & 1], gA, gB, KB0 + (s + 1) * BK, srow, schunk);
      mfma_step(As[s & 1], Bs[s & 1], wm, wn, l15, quad, accB);
    }
  }

  if (MODE == 0) {
#pragma unroll
    for (int mt = 0; mt < 4; ++mt)
#pragma unroll
      for (int nt = 0; nt < 3; ++nt) {
        const int gn = n0 + wn + nt * 16 + l15;
#pragma unroll
        for (int r = 0; r < 4; ++r) {
          const int gm = m0 + wm + mt * 16 + quad * 4 + r;  // C/D: col=lane&15,row=quad*4+reg
          c0[(size_t)gm * NCOL + gn] = accA[mt][nt][r];
        }
      }
    return;
  }

  // iter epilogue
  float sm[4][4];
#pragma unroll
  for (int mt = 0; mt < 4; ++mt)
#pragma unroll
    for (int r = 0; r < 4; ++r) {
      const int gm = m0 + wm + mt * 16 + quad * 4 + r;
      sm[mt][r] = 1.0f / fmaxf(sqrtf(nsq_prev[gm]), 1e-12f);
    }

  const bool has_hid = (n0 + BN) > OUTX;
#pragma unroll
  for (int mt = 0; mt < 4; ++mt) {
    float ss[4] = {0.f, 0.f, 0.f, 0.f};
#pragma unroll
    for (int nt = 0; nt < 3; ++nt) {
      const int gn = n0 + wn + nt * 16 + l15;
      const bool hid = gn >= OUTX;  // uniform per nt-tile (16 | boundaries)
#pragma unroll
      for (int r = 0; r < 4; ++r) {
        const int gm = m0 + wm + mt * 16 + quad * 4 + r;
        float v = c0[(size_t)gm * NCOL + gn] + accA[mt][nt][r] + sm[mt][r] * accB[mt][nt][r];
        v = fmaxf(v, 0.f);
        actn[(size_t)gm * L + INX + gn] = f2bf(v);
        if (hid) ss[r] += v * v;
      }
    }
    if (has_hid) {
#pragma unroll
      for (int r = 0; r < 4; ++r) {
        float sv = ss[r];
        sv += __shfl_xor(sv, 1);
        sv += __shfl_xor(sv, 2);
        sv += __shfl_xor(sv, 4);
        sv += __shfl_xor(sv, 8);
        if (l15 == 0)
          atomicAdd(&nsq_next[m0 + wm + mt * 16 + quad * 4 + r], sv);
      }
    }
  }
}

// ---- final: out = [x, bf(act_out), bf(act_hid)*s_final] in fp32 ----
__global__ void finalize(const float* __restrict__ x, const unsigned short* __restrict__ act,
                         const float* __restrict__ nsq_fin, float* __restrict__ out) {
  int i = blockIdx.x * 256 + threadIdx.x;
  int col = i & (L - 1), row = i >> 12;
  float v;
  if (col < INX) {
    v = x[(size_t)row * INX + col];
  } else {
    v = bf2f(act[i]);
    if (col >= INX + OUTX) v *= 1.0f / fmaxf(sqrtf(nsq_fin[row]), 1e-12f);
  }
  out[i] = v;
}

extern "C" void kernel_launch(void* const* d_in, const int* in_sizes, int n_in,
                              void* d_out, int out_size, void* d_ws, size_t ws_size,
                              hipStream_t stream) {
  const float* x = (const float*)d_in[0];
  // d_in[1] = y (unused: reference uses zeros_like(y))
  const float* W = (const float*)d_in[2];
  const float* A = (const float*)d_in[3];
  // d_in[4] = n (always 32)
  float* out = (float*)d_out;

  char* ws = (char*)d_ws;
  unsigned short* mwn  = (unsigned short*)(ws);                      // 25,165,824 B
  unsigned short* actA = (unsigned short*)(ws + 25165824);           //  8,388,608 B
  unsigned short* actB = (unsigned short*)(ws + 33554432);           //  8,388,608 B
  float* c0            = (float*)(ws + 41943040);                    // 12,582,912 B
  float* normsq        = (float*)(ws + 54525952);                    // 33*1024*4 B

  hipMemsetAsync(normsq, 0, (NITER + 1) * BATCH * sizeof(float), stream);
  prep_mwn<<<dim3(L / 32, NCOL / 32), 256, 0, stream>>>(W, A, mwn);
  init_act<<<(BATCH * L) / 256, 256, 0, stream>>>(x, actA);

  gemm_k<0><<<dim3(NCOL / BN, BATCH / BM), 256, 0, stream>>>(actA, mwn, nullptr, c0,
                                                             nullptr, nullptr);

  unsigned short* cur = actA;
  unsigned short* nxt = actB;
  for (int it = 0; it < NITER; ++it) {
    gemm_k<1><<<dim3(NCOL / BN, BATCH / BM), 256, 0, stream>>>(
        cur, mwn, nxt, c0, normsq + it * BATCH, normsq + (it + 1) * BATCH);
    unsigned short* tmp = cur; cur = nxt; nxt = tmp;
  }
  finalize<<<(BATCH * L) / 256, 256, 0, stream>>>(x, cur, normsq + NITER * BATCH, out);
}

// Round 3
// 1533.541 us; speedup vs baseline: 1.4663x; 1.4663x over previous
//
#include <hip/hip_runtime.h>
#include <stdint.h>
#include <stddef.h>

// BoltzmannMachine: 32 iters of act = relu(act @ (W*A^T)^T); act[:,:1024]=x;
// hid = act[:,2048:] row-normalized.
// R3: 512-thread blocks (8 waves -> 2 waves/SIMD at grid 256 = traffic-optimal
//     tiling) so ds_read/MFMA stalls of one wave are hidden by its SIMD partner.
//     c0 cached as bf16 (halves its per-iter re-read traffic).
//     Retained from R2: C0 x-part hoisted (K 4096->3072), 2-stage LDS dbuf with
//     single barrier per k-step, normalization folded via split accumulators.

#define L 4096
#define INX 1024
#define OUTX 1024
#define BATCH 1024
#define NCOL 3072
#define NITER 32

#define BM 128
#define BN 96
#define BK 64

typedef float floatx4 __attribute__((ext_vector_type(4)));
typedef short bf16x8 __attribute__((ext_vector_type(8)));

__device__ __forceinline__ unsigned short f2bf(float f) {
  unsigned int u = __float_as_uint(f);
  u += 0x7FFF + ((u >> 16) & 1);   // RNE
  return (unsigned short)(u >> 16);
}
__device__ __forceinline__ float bf2f(unsigned short h) {
  return __uint_as_float(((unsigned int)h) << 16);
}

__device__ __forceinline__ void load_lds_16B(const void* g, void* s) {
  __builtin_amdgcn_global_load_lds(
      (const __attribute__((address_space(1))) unsigned int*)g,
      (__attribute__((address_space(3))) unsigned int*)s, 16, 0, 0);
}

// ---- prep: mwn[i][j] = W[1024+i][j] * A[j][1024+i]  (bf16, 3072x4096) ----
__global__ void prep_mwn(const float* __restrict__ W, const float* __restrict__ A,
                         unsigned short* __restrict__ mwn) {
  __shared__ float At[32][33];
  const int tx = threadIdx.x & 31, ty = threadIdx.x >> 5;
  const int j0 = blockIdx.x * 32, i0 = blockIdx.y * 32;
#pragma unroll
  for (int r = 0; r < 4; ++r) {
    int a = ty + 8 * r;
    At[a][tx] = A[(size_t)(j0 + a) * L + INX + i0 + tx];
  }
  __syncthreads();
#pragma unroll
  for (int r = 0; r < 4; ++r) {
    int ii = ty + 8 * r;
    float w = W[(size_t)(INX + i0 + ii) * L + j0 + tx];
    float av = At[tx][ii];
    mwn[(size_t)(i0 + ii) * L + j0 + tx] = f2bf(w * av);
  }
}

// ---- init actA: cols<1024 = bf16(x), else 0 ----
__global__ void init_act(const float* __restrict__ x, unsigned short* __restrict__ actA) {
  int i = blockIdx.x * 256 + threadIdx.x;
  int col = i & (L - 1), row = i >> 12;
  actA[i] = (col < INX) ? f2bf(x[(size_t)row * INX + col]) : (unsigned short)0;
}

// staging (512 threads): thread t loads 16B chunks; LDS dest lane-contiguous
// (global_load_lds requirement); global chunk XOR-swizzled by row&7 so
// ds_read_b128 fragment reads are bank-conflict-free without padding.
// A: rows (t>>3) and (t>>3)+64.  B: row (t>>3); rows 64..95 by waves 0-3.
__device__ __forceinline__ void stage(unsigned short* As, unsigned short* Bs,
                                      const unsigned short* gA, const unsigned short* gB,
                                      int kb, int t) {
  const int srow = t >> 3, schunk = t & 7;
  const int o = srow * BK + schunk * 8;
  load_lds_16B(gA + kb, &As[o]);
  load_lds_16B(gA + (size_t)64 * L + kb, &As[o + 64 * BK]);
  load_lds_16B(gB + kb, &Bs[o]);
  if (t < 256)  // wave-uniform (waves 0-3)
    load_lds_16B(gB + (size_t)64 * L + kb, &Bs[o + 64 * BK]);
}

// wave tile 32x48: 2 A-frags x 3 B-frags
__device__ __forceinline__ void mfma_step(const unsigned short* As, const unsigned short* Bs,
                                          int wm, int wn, int l15, int quad,
                                          floatx4 acc[2][3]) {
#pragma unroll
  for (int kk = 0; kk < 2; ++kk) {
    bf16x8 af[2], bfr[3];
    const int c = kk * 4 + quad;
#pragma unroll
    for (int mt = 0; mt < 2; ++mt) {
      int r = wm + mt * 16 + l15;
      af[mt] = *(const bf16x8*)&As[r * BK + ((c ^ (r & 7)) * 8)];
    }
#pragma unroll
    for (int nt = 0; nt < 3; ++nt) {
      int r = wn + nt * 16 + l15;
      bfr[nt] = *(const bf16x8*)&Bs[r * BK + ((c ^ (r & 7)) * 8)];
    }
#pragma unroll
    for (int mt = 0; mt < 2; ++mt)
#pragma unroll
      for (int nt = 0; nt < 3; ++nt)
        acc[mt][nt] = __builtin_amdgcn_mfma_f32_16x16x32_bf16(af[mt], bfr[nt],
                                                              acc[mt][nt], 0, 0, 0);
  }
}

// MODE 0: C0 pass, K=[0,1024), c0 = x-part (bf16 store, no relu).
// MODE 1: iter pass, K=[1024,4096), acc split at k=2048 (accA out / accB hid),
//         result = C0 + accA + s_prev[m]*accB, relu, bf16 store, hid sumsq atomics.
template<int MODE>
__global__ __launch_bounds__(512, 1) void gemm_k(
    const unsigned short* __restrict__ act,
    const unsigned short* __restrict__ mwn,
    unsigned short* __restrict__ actn,
    unsigned short* __restrict__ c0,
    const float* __restrict__ nsq_prev,
    float* __restrict__ nsq_next) {
  __shared__ alignas(16) unsigned short As[2][BM * BK];
  __shared__ alignas(16) unsigned short Bs[2][BN * BK];
  const int t = threadIdx.x;
  const int lane = t & 63;
  const int wave = t >> 6;          // 0..7
  const int wm = (wave & 3) * 32;   // 4 m-positions
  const int wn = (wave >> 2) * 48;  // 2 n-positions
  const int l15 = lane & 15;
  const int quad = lane >> 4;
  const int m0 = blockIdx.y * BM;
  const int n0 = blockIdx.x * BN;

  const int srow = t >> 3;
  const int schunk = t & 7;
  const int gchunk = schunk ^ (srow & 7);
  const unsigned short* gA = act + (size_t)(m0 + srow) * L + gchunk * 8;
  const unsigned short* gB = mwn + (size_t)(n0 + srow) * L + gchunk * 8;

  const int KB0 = MODE ? INX : 0;
  const int NS = MODE ? 48 : 16;

  floatx4 accA[2][3], accB[2][3];
#pragma unroll
  for (int i = 0; i < 2; ++i)
#pragma unroll
    for (int j = 0; j < 3; ++j) {
      accA[i][j] = (floatx4){0.f, 0.f, 0.f, 0.f};
      if (MODE) accB[i][j] = (floatx4){0.f, 0.f, 0.f, 0.f};
    }

  stage(As[0], Bs[0], gA, gB, KB0, t);
  int s = 0;
  // first sub-loop: MODE0 all 16 steps; MODE1 k=[1024,2048) -> accA
  for (; s < 16; ++s) {
    __syncthreads();  // drains vmcnt -> buf[s&1] ready; prev compute done
    if (s + 1 < NS)
      stage(As[(s + 1) & 1], Bs[(s + 1) & 1], gA, gB, KB0 + (s + 1) * BK, t);
    mfma_step(As[s & 1], Bs[s & 1], wm, wn, l15, quad, accA);
  }
  if (MODE) {
    // second sub-loop: k=[2048,4096) -> accB (hid contribution, scaled in epilogue)
    for (; s < NS; ++s) {
      __syncthreads();
      if (s + 1 < NS)
        stage(As[(s + 1) & 1], Bs[(s + 1) & 1], gA, gB, KB0 + (s + 1) * BK, t);
      mfma_step(As[s & 1], Bs[s & 1], wm, wn, l15, quad, accB);
    }
  }

  if (MODE == 0) {
#pragma unroll
    for (int mt = 0; mt < 2; ++mt)
#pragma unroll
      for (int nt = 0; nt < 3; ++nt) {
        const int gn = n0 + wn + nt * 16 + l15;
#pragma unroll
        for (int r = 0; r < 4; ++r) {
          const int gm = m0 + wm + mt * 16 + quad * 4 + r;  // C/D: col=lane&15,row=quad*4+reg
          c0[(size_t)gm * NCOL + gn] = f2bf(accA[mt][nt][r]);
        }
      }
    return;
  }

  // iter epilogue
  float sm[2][4];
#pragma unroll
  for (int mt = 0; mt < 2; ++mt)
#pragma unroll
    for (int r = 0; r < 4; ++r) {
      const int gm = m0 + wm + mt * 16 + quad * 4 + r;
      sm[mt][r] = 1.0f / fmaxf(sqrtf(nsq_prev[gm]), 1e-12f);
    }

  const bool has_hid = (n0 + BN) > OUTX;
#pragma unroll
  for (int mt = 0; mt < 2; ++mt) {
    float ss[4] = {0.f, 0.f, 0.f, 0.f};
#pragma unroll
    for (int nt = 0; nt < 3; ++nt) {
      const int gn = n0 + wn + nt * 16 + l15;
      const bool hid = gn >= OUTX;  // uniform per nt-tile (16 | boundaries)
#pragma unroll
      for (int r = 0; r < 4; ++r) {
        const int gm = m0 + wm + mt * 16 + quad * 4 + r;
        float v = bf2f(c0[(size_t)gm * NCOL + gn]) + accA[mt][nt][r]
                  + sm[mt][r] * accB[mt][nt][r];
        v = fmaxf(v, 0.f);
        actn[(size_t)gm * L + INX + gn] = f2bf(v);
        if (hid) ss[r] += v * v;
      }
    }
    if (has_hid) {
#pragma unroll
      for (int r = 0; r < 4; ++r) {
        float sv = ss[r];
        sv += __shfl_xor(sv, 1);
        sv += __shfl_xor(sv, 2);
        sv += __shfl_xor(sv, 4);
        sv += __shfl_xor(sv, 8);
        if (l15 == 0)
          atomicAdd(&nsq_next[m0 + wm + mt * 16 + quad * 4 + r], sv);
      }
    }
  }
}

// ---- final: out = [x, bf(act_out), bf(act_hid)*s_final] in fp32 ----
__global__ void finalize(const float* __restrict__ x, const unsigned short* __restrict__ act,
                         const float* __restrict__ nsq_fin, float* __restrict__ out) {
  int i = blockIdx.x * 256 + threadIdx.x;
  int col = i & (L - 1), row = i >> 12;
  float v;
  if (col < INX) {
    v = x[(size_t)row * INX + col];
  } else {
    v = bf2f(act[i]);
    if (col >= INX + OUTX) v *= 1.0f / fmaxf(sqrtf(nsq_fin[row]), 1e-12f);
  }
  out[i] = v;
}

extern "C" void kernel_launch(void* const* d_in, const int* in_sizes, int n_in,
                              void* d_out, int out_size, void* d_ws, size_t ws_size,
                              hipStream_t stream) {
  const float* x = (const float*)d_in[0];
  // d_in[1] = y (unused: reference uses zeros_like(y))
  const float* W = (const float*)d_in[2];
  const float* A = (const float*)d_in[3];
  // d_in[4] = n (always 32)
  float* out = (float*)d_out;

  char* ws = (char*)d_ws;
  unsigned short* mwn  = (unsigned short*)(ws);                      // 25,165,824 B
  unsigned short* actA = (unsigned short*)(ws + 25165824);           //  8,388,608 B
  unsigned short* actB = (unsigned short*)(ws + 33554432);           //  8,388,608 B
  unsigned short* c0   = (unsigned short*)(ws + 41943040);           //  6,291,456 B (bf16)
  float* normsq        = (float*)(ws + 48234496);                    // 33*1024*4 B

  hipMemsetAsync(normsq, 0, (NITER + 1) * BATCH * sizeof(float), stream);
  prep_mwn<<<dim3(L / 32, NCOL / 32), 256, 0, stream>>>(W, A, mwn);
  init_act<<<(BATCH * L) / 256, 256, 0, stream>>>(x, actA);

  gemm_k<0><<<dim3(NCOL / BN, BATCH / BM), 512, 0, stream>>>(actA, mwn, nullptr, c0,
                                                             nullptr, nullptr);

  unsigned short* cur = actA;
  unsigned short* nxt = actB;
  for (int it = 0; it < NITER; ++it) {
    gemm_k<1><<<dim3(NCOL / BN, BATCH / BM), 512, 0, stream>>>(
        cur, mwn, nxt, c0, normsq + it * BATCH, normsq + (it + 1) * BATCH);
    unsigned short* tmp = cur; cur = nxt; nxt = tmp;
  }
  finalize<<<(BATCH * L) / 256, 256, 0, stream>>>(x, cur, normsq + NITER * BATCH, out);
}

// Round 4
// 1393.086 us; speedup vs baseline: 1.6141x; 1.1008x over previous
//
#include <hip/hip_runtime.h>
#include <stdint.h>
#include <stddef.h>

// BoltzmannMachine: 32 iters of act = relu(act @ (W*A^T)^T); act[:,:1024]=x;
// hid = act[:,2048:] row-normalized.
// R4: BM 128->64, 256-thread blocks (4 waves), grid 32x16 = 512 blocks = 2
//     blocks/CU with INDEPENDENT barriers -> cross-block latency overlap
//     (m97/m114 regime). R3's single-barrier domain left all 8 waves/CU
//     draining vmcnt together. LDS dbuf 40 KB; __launch_bounds__(256,4).
//     Retained: C0 x-part hoisted (K 4096->3072), 2-stage LDS dbuf single
//     barrier/step, XOR-swizzled staging, normalization folded via split
//     accumulators, c0 in bf16.

#define L 4096
#define INX 1024
#define OUTX 1024
#define BATCH 1024
#define NCOL 3072
#define NITER 32

#define BM 64
#define BN 96
#define BK 64

typedef float floatx4 __attribute__((ext_vector_type(4)));
typedef short bf16x8 __attribute__((ext_vector_type(8)));

__device__ __forceinline__ unsigned short f2bf(float f) {
  unsigned int u = __float_as_uint(f);
  u += 0x7FFF + ((u >> 16) & 1);   // RNE
  return (unsigned short)(u >> 16);
}
__device__ __forceinline__ float bf2f(unsigned short h) {
  return __uint_as_float(((unsigned int)h) << 16);
}

__device__ __forceinline__ void load_lds_16B(const void* g, void* s) {
  __builtin_amdgcn_global_load_lds(
      (const __attribute__((address_space(1))) unsigned int*)g,
      (__attribute__((address_space(3))) unsigned int*)s, 16, 0, 0);
}

// ---- prep: mwn[i][j] = W[1024+i][j] * A[j][1024+i]  (bf16, 3072x4096) ----
__global__ void prep_mwn(const float* __restrict__ W, const float* __restrict__ A,
                         unsigned short* __restrict__ mwn) {
  __shared__ float At[32][33];
  const int tx = threadIdx.x & 31, ty = threadIdx.x >> 5;
  const int j0 = blockIdx.x * 32, i0 = blockIdx.y * 32;
#pragma unroll
  for (int r = 0; r < 4; ++r) {
    int a = ty + 8 * r;
    At[a][tx] = A[(size_t)(j0 + a) * L + INX + i0 + tx];
  }
  __syncthreads();
#pragma unroll
  for (int r = 0; r < 4; ++r) {
    int ii = ty + 8 * r;
    float w = W[(size_t)(INX + i0 + ii) * L + j0 + tx];
    float av = At[tx][ii];
    mwn[(size_t)(i0 + ii) * L + j0 + tx] = f2bf(w * av);
  }
}

// ---- init actA: cols<1024 = bf16(x), else 0 ----
__global__ void init_act(const float* __restrict__ x, unsigned short* __restrict__ actA) {
  int i = blockIdx.x * 256 + threadIdx.x;
  int col = i & (L - 1), row = i >> 12;
  actA[i] = (col < INX) ? f2bf(x[(size_t)row * INX + col]) : (unsigned short)0;
}

// staging (256 threads, BM=64/BN=96/BK=64): thread t loads 16B chunks; LDS dest
// lane-contiguous (global_load_lds requirement); global chunk XOR-swizzled by
// row&7 so ds_read_b128 fragment reads are bank-conflict-free without padding.
// 5 loads/thread: A rows srow,srow+32; B rows srow,srow+32,srow+64.
__device__ __forceinline__ void stage(unsigned short* As, unsigned short* Bs,
                                      const unsigned short* gA, const unsigned short* gB,
                                      int kb, int t) {
  const int srow = t >> 3, schunk = t & 7;
  const int o = srow * BK + schunk * 8;
  load_lds_16B(gA + kb, &As[o]);
  load_lds_16B(gA + (size_t)32 * L + kb, &As[o + 32 * BK]);
  load_lds_16B(gB + kb, &Bs[o]);
  load_lds_16B(gB + (size_t)32 * L + kb, &Bs[o + 32 * BK]);
  load_lds_16B(gB + (size_t)64 * L + kb, &Bs[o + 64 * BK]);
}

// wave tile 32x48: 2 A-frags x 3 B-frags
__device__ __forceinline__ void mfma_step(const unsigned short* As, const unsigned short* Bs,
                                          int wm, int wn, int l15, int quad,
                                          floatx4 acc[2][3]) {
#pragma unroll
  for (int kk = 0; kk < 2; ++kk) {
    bf16x8 af[2], bfr[3];
    const int c = kk * 4 + quad;
#pragma unroll
    for (int mt = 0; mt < 2; ++mt) {
      int r = wm + mt * 16 + l15;
      af[mt] = *(const bf16x8*)&As[r * BK + ((c ^ (r & 7)) * 8)];
    }
#pragma unroll
    for (int nt = 0; nt < 3; ++nt) {
      int r = wn + nt * 16 + l15;
      bfr[nt] = *(const bf16x8*)&Bs[r * BK + ((c ^ (r & 7)) * 8)];
    }
#pragma unroll
    for (int mt = 0; mt < 2; ++mt)
#pragma unroll
      for (int nt = 0; nt < 3; ++nt)
        acc[mt][nt] = __builtin_amdgcn_mfma_f32_16x16x32_bf16(af[mt], bfr[nt],
                                                              acc[mt][nt], 0, 0, 0);
  }
}

// MODE 0: C0 pass, K=[0,1024), c0 = x-part (bf16 store, no relu).
// MODE 1: iter pass, K=[1024,4096), acc split at k=2048 (accA out / accB hid),
//         result = C0 + accA + s_prev[m]*accB, relu, bf16 store, hid sumsq atomics.
template<int MODE>
__global__ __launch_bounds__(256, 4) void gemm_k(
    const unsigned short* __restrict__ act,
    const unsigned short* __restrict__ mwn,
    unsigned short* __restrict__ actn,
    unsigned short* __restrict__ c0,
    const float* __restrict__ nsq_prev,
    float* __restrict__ nsq_next) {
  __shared__ alignas(16) unsigned short As[2][BM * BK];
  __shared__ alignas(16) unsigned short Bs[2][BN * BK];
  const int t = threadIdx.x;
  const int lane = t & 63;
  const int wave = t >> 6;          // 0..3
  const int wm = (wave & 1) * 32;
  const int wn = (wave >> 1) * 48;
  const int l15 = lane & 15;
  const int quad = lane >> 4;
  const int m0 = blockIdx.y * BM;
  const int n0 = blockIdx.x * BN;

  const int srow = t >> 3;
  const int schunk = t & 7;
  const int gchunk = schunk ^ (srow & 7);
  const unsigned short* gA = act + (size_t)(m0 + srow) * L + gchunk * 8;
  const unsigned short* gB = mwn + (size_t)(n0 + srow) * L + gchunk * 8;

  const int KB0 = MODE ? INX : 0;
  const int NS = MODE ? 48 : 16;

  floatx4 accA[2][3], accB[2][3];
#pragma unroll
  for (int i = 0; i < 2; ++i)
#pragma unroll
    for (int j = 0; j < 3; ++j) {
      accA[i][j] = (floatx4){0.f, 0.f, 0.f, 0.f};
      if (MODE) accB[i][j] = (floatx4){0.f, 0.f, 0.f, 0.f};
    }

  stage(As[0], Bs[0], gA, gB, KB0, t);
  int s = 0;
  // first sub-loop: MODE0 all 16 steps; MODE1 k=[1024,2048) -> accA
  for (; s < 16; ++s) {
    __syncthreads();  // drains vmcnt -> buf[s&1] ready; prev compute done
    if (s + 1 < NS)
      stage(As[(s + 1) & 1], Bs[(s + 1) & 1], gA, gB, KB0 + (s + 1) * BK, t);
    mfma_step(As[s & 1], Bs[s & 1], wm, wn, l15, quad, accA);
  }
  if (MODE) {
    // second sub-loop: k=[2048,4096) -> accB (hid contribution, scaled in epilogue)
    for (; s < NS; ++s) {
      __syncthreads();
      if (s + 1 < NS)
        stage(As[(s + 1) & 1], Bs[(s + 1) & 1], gA, gB, KB0 + (s + 1) * BK, t);
      mfma_step(As[s & 1], Bs[s & 1], wm, wn, l15, quad, accB);
    }
  }

  if (MODE == 0) {
#pragma unroll
    for (int mt = 0; mt < 2; ++mt)
#pragma unroll
      for (int nt = 0; nt < 3; ++nt) {
        const int gn = n0 + wn + nt * 16 + l15;
#pragma unroll
        for (int r = 0; r < 4; ++r) {
          const int gm = m0 + wm + mt * 16 + quad * 4 + r;  // C/D: col=lane&15,row=quad*4+reg
          c0[(size_t)gm * NCOL + gn] = f2bf(accA[mt][nt][r]);
        }
      }
    return;
  }

  // iter epilogue
  float sm[2][4];
#pragma unroll
  for (int mt = 0; mt < 2; ++mt)
#pragma unroll
    for (int r = 0; r < 4; ++r) {
      const int gm = m0 + wm + mt * 16 + quad * 4 + r;
      sm[mt][r] = 1.0f / fmaxf(sqrtf(nsq_prev[gm]), 1e-12f);
    }

  const bool has_hid = (n0 + BN) > OUTX;
#pragma unroll
  for (int mt = 0; mt < 2; ++mt) {
    float ss[4] = {0.f, 0.f, 0.f, 0.f};
#pragma unroll
    for (int nt = 0; nt < 3; ++nt) {
      const int gn = n0 + wn + nt * 16 + l15;
      const bool hid = gn >= OUTX;  // uniform per nt-tile (16 | boundaries)
#pragma unroll
      for (int r = 0; r < 4; ++r) {
        const int gm = m0 + wm + mt * 16 + quad * 4 + r;
        float v = bf2f(c0[(size_t)gm * NCOL + gn]) + accA[mt][nt][r]
                  + sm[mt][r] * accB[mt][nt][r];
        v = fmaxf(v, 0.f);
        actn[(size_t)gm * L + INX + gn] = f2bf(v);
        if (hid) ss[r] += v * v;
      }
    }
    if (has_hid) {
#pragma unroll
      for (int r = 0; r < 4; ++r) {
        float sv = ss[r];
        sv += __shfl_xor(sv, 1);
        sv += __shfl_xor(sv, 2);
        sv += __shfl_xor(sv, 4);
        sv += __shfl_xor(sv, 8);
        if (l15 == 0)
          atomicAdd(&nsq_next[m0 + wm + mt * 16 + quad * 4 + r], sv);
      }
    }
  }
}

// ---- final: out = [x, bf(act_out), bf(act_hid)*s_final] in fp32 ----
__global__ void finalize(const float* __restrict__ x, const unsigned short* __restrict__ act,
                         const float* __restrict__ nsq_fin, float* __restrict__ out) {
  int i = blockIdx.x * 256 + threadIdx.x;
  int col = i & (L - 1), row = i >> 12;
  float v;
  if (col < INX) {
    v = x[(size_t)row * INX + col];
  } else {
    v = bf2f(act[i]);
    if (col >= INX + OUTX) v *= 1.0f / fmaxf(sqrtf(nsq_fin[row]), 1e-12f);
  }
  out[i] = v;
}

extern "C" void kernel_launch(void* const* d_in, const int* in_sizes, int n_in,
                              void* d_out, int out_size, void* d_ws, size_t ws_size,
                              hipStream_t stream) {
  const float* x = (const float*)d_in[0];
  // d_in[1] = y (unused: reference uses zeros_like(y))
  const float* W = (const float*)d_in[2];
  const float* A = (const float*)d_in[3];
  // d_in[4] = n (always 32)
  float* out = (float*)d_out;

  char* ws = (char*)d_ws;
  unsigned short* mwn  = (unsigned short*)(ws);                      // 25,165,824 B
  unsigned short* actA = (unsigned short*)(ws + 25165824);           //  8,388,608 B
  unsigned short* actB = (unsigned short*)(ws + 33554432);           //  8,388,608 B
  unsigned short* c0   = (unsigned short*)(ws + 41943040);           //  6,291,456 B (bf16)
  float* normsq        = (float*)(ws + 48234496);                    // 33*1024*4 B

  hipMemsetAsync(normsq, 0, (NITER + 1) * BATCH * sizeof(float), stream);
  prep_mwn<<<dim3(L / 32, NCOL / 32), 256, 0, stream>>>(W, A, mwn);
  init_act<<<(BATCH * L) / 256, 256, 0, stream>>>(x, actA);

  gemm_k<0><<<dim3(NCOL / BN, BATCH / BM), 256, 0, stream>>>(actA, mwn, nullptr, c0,
                                                             nullptr, nullptr);

  unsigned short* cur = actA;
  unsigned short* nxt = actB;
  for (int it = 0; it < NITER; ++it) {
    gemm_k<1><<<dim3(NCOL / BN, BATCH / BM), 256, 0, stream>>>(
        cur, mwn, nxt, c0, normsq + it * BATCH, normsq + (it + 1) * BATCH);
    unsigned short* tmp = cur; cur = nxt; nxt = tmp;
  }
  finalize<<<(BATCH * L) / 256, 256, 0, stream>>>(x, cur, normsq + NITER * BATCH, out);
}